// Round 1
// baseline (273.406 us; speedup 1.0000x reference)
//
#include <hip/hip_runtime.h>
#include <math.h>

#define NB 256          // batches
#define NPT 8192        // points per batch
#define SPLITS 4        // blocks per batch for the streaming passes
#define CHUNK (NPT / SPLITS)
#define THREADS 256
#define CLAMPV 10.0f

// ---------------------------------------------------------------------------
// Pass 1: per (batch, split) partial sums: sum(pred)[3], sum(true)[3],
//         M[i][j] = sum pred_i * true_j [9]  -> stats[blk*16 + 0..14]
// ---------------------------------------------------------------------------
__global__ __launch_bounds__(THREADS) void cov_kernel(
    const float* __restrict__ pred, const float* __restrict__ tru,
    float* __restrict__ stats)
{
    const int blk = blockIdx.x;
    const int b  = blk >> 2;   // / SPLITS
    const int sp = blk & 3;    // % SPLITS
    const float* P = pred + ((size_t)b * NPT + (size_t)sp * CHUNK) * 3;
    const float* T = tru  + ((size_t)b * NPT + (size_t)sp * CHUNK) * 3;

    float acc[15];
#pragma unroll
    for (int i = 0; i < 15; ++i) acc[i] = 0.f;

    for (int n = threadIdx.x; n < CHUNK; n += THREADS) {
        const float px = P[3*n+0], py = P[3*n+1], pz = P[3*n+2];
        const float tx = T[3*n+0], ty = T[3*n+1], tz = T[3*n+2];
        acc[0] += px; acc[1] += py; acc[2] += pz;
        acc[3] += tx; acc[4] += ty; acc[5] += tz;
        acc[6]  += px*tx; acc[7]  += px*ty; acc[8]  += px*tz;
        acc[9]  += py*tx; acc[10] += py*ty; acc[11] += py*tz;
        acc[12] += pz*tx; acc[13] += pz*ty; acc[14] += pz*tz;
    }
#pragma unroll
    for (int i = 0; i < 15; ++i)
        for (int off = 32; off > 0; off >>= 1)
            acc[i] += __shfl_down(acc[i], off, 64);

    __shared__ float smem[THREADS/64][15];
    const int wave = threadIdx.x >> 6, lane = threadIdx.x & 63;
    if (lane == 0) {
#pragma unroll
        for (int i = 0; i < 15; ++i) smem[wave][i] = acc[i];
    }
    __syncthreads();
    if (threadIdx.x < 15) {
        float s = 0.f;
#pragma unroll
        for (int w = 0; w < THREADS/64; ++w) s += smem[w][threadIdx.x];
        stats[(size_t)blk * 16 + threadIdx.x] = s;
    }
}

// ---------------------------------------------------------------------------
// Pass 2: one thread per batch. fp64 Jacobi SVD of H (3x3) via eig(H^T H),
// Kabsch R = V U^T with det fix on the smallest-singular-value V column,
// t = cB - R cA.  Writes RT[b*12] = R row-major (9) + t (3) as fp32.
// ---------------------------------------------------------------------------
__device__ inline double det3(const double m[3][3]) {
    return m[0][0]*(m[1][1]*m[2][2]-m[1][2]*m[2][1])
         - m[0][1]*(m[1][0]*m[2][2]-m[1][2]*m[2][0])
         + m[0][2]*(m[1][0]*m[2][1]-m[1][1]*m[2][0]);
}

__global__ void svd_kernel(const float* __restrict__ stats, float* __restrict__ RT)
{
    const int b = blockIdx.x * blockDim.x + threadIdx.x;
    if (b >= NB) return;

    double sA[3] = {0,0,0}, sB[3] = {0,0,0}, M[9] = {0,0,0,0,0,0,0,0,0};
    for (int sp = 0; sp < SPLITS; ++sp) {
        const float* st = stats + ((size_t)(b * SPLITS + sp)) * 16;
        for (int i = 0; i < 3; ++i) sA[i] += st[i];
        for (int i = 0; i < 3; ++i) sB[i] += st[3 + i];
        for (int i = 0; i < 9; ++i) M[i]  += st[6 + i];
    }
    double cA[3], cB[3];
    for (int i = 0; i < 3; ++i) { cA[i] = sA[i] / NPT; cB[i] = sB[i] / NPT; }

    double H[3][3];
    for (int i = 0; i < 3; ++i)
        for (int j = 0; j < 3; ++j)
            H[i][j] = M[i*3 + j] - (double)NPT * cA[i] * cB[j];

    // A = H^T H (symmetric PSD)
    double A[3][3];
    for (int i = 0; i < 3; ++i)
        for (int j = 0; j < 3; ++j) {
            double s = 0.0;
            for (int k = 0; k < 3; ++k) s += H[k][i] * H[k][j];
            A[i][j] = s;
        }
    double V[3][3] = {{1,0,0},{0,1,0},{0,0,1}};
    const int PQ[3][2] = {{0,1},{0,2},{1,2}};
    for (int sweep = 0; sweep < 15; ++sweep) {
        for (int r = 0; r < 3; ++r) {
            const int p = PQ[r][0], q = PQ[r][1];
            const double apq = A[p][q];
            if (fabs(apq) < 1e-300) continue;
            const double theta = (A[q][q] - A[p][p]) / (2.0 * apq);
            const double t = copysign(1.0, theta) / (fabs(theta) + sqrt(theta*theta + 1.0));
            const double c = 1.0 / sqrt(t*t + 1.0);
            const double s = t * c;
            for (int k = 0; k < 3; ++k) {           // A <- A G
                const double akp = A[k][p], akq = A[k][q];
                A[k][p] = c*akp - s*akq;
                A[k][q] = s*akp + c*akq;
            }
            for (int k = 0; k < 3; ++k) {           // A <- G^T A
                const double apk = A[p][k], aqk = A[q][k];
                A[p][k] = c*apk - s*aqk;
                A[q][k] = s*apk + c*aqk;
            }
            for (int k = 0; k < 3; ++k) {           // V <- V G
                const double vkp = V[k][p], vkq = V[k][q];
                V[k][p] = c*vkp - s*vkq;
                V[k][q] = s*vkp + c*vkq;
            }
        }
    }
    double eig[3] = {A[0][0], A[1][1], A[2][2]};
    int idx[3] = {0, 1, 2};
    if (eig[idx[0]] < eig[idx[1]]) { int t_ = idx[0]; idx[0] = idx[1]; idx[1] = t_; }
    if (eig[idx[0]] < eig[idx[2]]) { int t_ = idx[0]; idx[0] = idx[2]; idx[2] = t_; }
    if (eig[idx[1]] < eig[idx[2]]) { int t_ = idx[1]; idx[1] = idx[2]; idx[2] = t_; }

    double Vc[3][3], Uc[3][3];
    for (int i = 0; i < 3; ++i) {
        const int j = idx[i];
        for (int r = 0; r < 3; ++r) Vc[r][i] = V[r][j];
    }
    for (int i = 0; i < 3; ++i) {
        double u[3];
        for (int r = 0; r < 3; ++r)
            u[r] = H[r][0]*Vc[0][i] + H[r][1]*Vc[1][i] + H[r][2]*Vc[2][i];
        const double nrm = sqrt(u[0]*u[0] + u[1]*u[1] + u[2]*u[2]);
        if (nrm > 1e-30) {
            for (int r = 0; r < 3; ++r) Uc[r][i] = u[r] / nrm;
        } else if (i == 2) {  // degenerate guard (never hit for random data)
            Uc[0][2] = Uc[1][0]*Uc[2][1] - Uc[2][0]*Uc[1][1];
            Uc[1][2] = Uc[2][0]*Uc[0][1] - Uc[0][0]*Uc[2][1];
            Uc[2][2] = Uc[0][0]*Uc[1][1] - Uc[1][0]*Uc[0][1];
        } else {
            for (int r = 0; r < 3; ++r) Uc[r][i] = (r == i) ? 1.0 : 0.0;
        }
    }
    if (det3(Uc) * det3(Vc) < 0.0)
        for (int r = 0; r < 3; ++r) Vc[r][2] = -Vc[r][2];

    // R = V U^T : R[i][k] = sum_j Vc[i][j] * Uc[k][j]
    double R[3][3];
    for (int i = 0; i < 3; ++i)
        for (int k = 0; k < 3; ++k)
            R[i][k] = Vc[i][0]*Uc[k][0] + Vc[i][1]*Uc[k][1] + Vc[i][2]*Uc[k][2];
    double tv[3];
    for (int i = 0; i < 3; ++i)
        tv[i] = cB[i] - (R[i][0]*cA[0] + R[i][1]*cA[1] + R[i][2]*cA[2]);

    float* o = RT + (size_t)b * 12;
    for (int i = 0; i < 3; ++i)
        for (int j = 0; j < 3; ++j)
            o[i*3 + j] = (float)R[i][j];
    for (int i = 0; i < 3; ++i) o[9 + i] = (float)tv[i];
}

// ---------------------------------------------------------------------------
// Pass 3: clamped distance partial sums per (batch, split) block.
// pred_aligned[n,j] = sum_i pred[n,i] * R[i][j] + t[j]   (pred @ R, faithful)
// ---------------------------------------------------------------------------
__global__ __launch_bounds__(THREADS) void dist_kernel(
    const float* __restrict__ pred, const float* __restrict__ tru,
    const float* __restrict__ RT, float* __restrict__ partial)
{
    const int blk = blockIdx.x;
    const int b  = blk >> 2;
    const int sp = blk & 3;
    const float* P = pred + ((size_t)b * NPT + (size_t)sp * CHUNK) * 3;
    const float* T = tru  + ((size_t)b * NPT + (size_t)sp * CHUNK) * 3;
    const float* rt = RT + (size_t)b * 12;
    const float R00 = rt[0], R01 = rt[1], R02 = rt[2];
    const float R10 = rt[3], R11 = rt[4], R12 = rt[5];
    const float R20 = rt[6], R21 = rt[7], R22 = rt[8];
    const float t0 = rt[9], t1 = rt[10], t2 = rt[11];

    float acc = 0.f;
    for (int n = threadIdx.x; n < CHUNK; n += THREADS) {
        const float px = P[3*n+0], py = P[3*n+1], pz = P[3*n+2];
        const float tx = T[3*n+0], ty = T[3*n+1], tz = T[3*n+2];
        const float ax = px*R00 + py*R10 + pz*R20 + t0;
        const float ay = px*R01 + py*R11 + pz*R21 + t1;
        const float az = px*R02 + py*R12 + pz*R22 + t2;
        const float dx = ax - tx, dy = ay - ty, dz = az - tz;
        const float d = sqrtf(dx*dx + dy*dy + dz*dz);
        acc += fminf(d, CLAMPV);
    }
    for (int off = 32; off > 0; off >>= 1)
        acc += __shfl_down(acc, off, 64);
    __shared__ float smem[THREADS/64];
    const int wave = threadIdx.x >> 6, lane = threadIdx.x & 63;
    if (lane == 0) smem[wave] = acc;
    __syncthreads();
    if (threadIdx.x == 0) {
        float s = 0.f;
#pragma unroll
        for (int w = 0; w < THREADS/64; ++w) s += smem[w];
        partial[blk] = s;
    }
}

// ---------------------------------------------------------------------------
// Pass 4: reduce NB*SPLITS partials -> global mean
// ---------------------------------------------------------------------------
__global__ __launch_bounds__(THREADS) void finalize_kernel(
    const float* __restrict__ partial, float* __restrict__ out)
{
    float acc = 0.f;
    for (int i = threadIdx.x; i < NB * SPLITS; i += THREADS) acc += partial[i];
    for (int off = 32; off > 0; off >>= 1)
        acc += __shfl_down(acc, off, 64);
    __shared__ float smem[THREADS/64];
    const int wave = threadIdx.x >> 6, lane = threadIdx.x & 63;
    if (lane == 0) smem[wave] = acc;
    __syncthreads();
    if (threadIdx.x == 0) {
        float s = 0.f;
#pragma unroll
        for (int w = 0; w < THREADS/64; ++w) s += smem[w];
        out[0] = s / 2097152.0f;   // B*N = 256*8192
    }
}

extern "C" void kernel_launch(void* const* d_in, const int* in_sizes, int n_in,
                              void* d_out, int out_size, void* d_ws, size_t ws_size,
                              hipStream_t stream)
{
    // inputs: [0] pred_frames (unused), [1] true_frames (unused),
    //         [2] pred_pos [256,8192,3] f32, [3] true_pos [256,8192,3] f32
    const float* pred_pos = (const float*)d_in[2];
    const float* true_pos = (const float*)d_in[3];
    float* out = (float*)d_out;

    float* ws      = (float*)d_ws;
    float* stats   = ws;                          // NB*SPLITS*16 = 16384 floats
    float* RT      = ws + (size_t)NB * SPLITS * 16; // NB*12 = 3072 floats
    float* partial = RT + (size_t)NB * 12;        // NB*SPLITS = 1024 floats

    cov_kernel<<<NB * SPLITS, THREADS, 0, stream>>>(pred_pos, true_pos, stats);
    svd_kernel<<<1, NB, 0, stream>>>(stats, RT);
    dist_kernel<<<NB * SPLITS, THREADS, 0, stream>>>(pred_pos, true_pos, RT, partial);
    finalize_kernel<<<1, THREADS, 0, stream>>>(partial, out);
}